// Round 1
// baseline (265.419 us; speedup 1.0000x reference)
//
#include <hip/hip_runtime.h>

// multihead self-attention: B=4 S=2048 D=1024 H=16 DK=64, causal, RoPE(theta=1e4)
// f16 pipeline, 4 dispatches:
//   cvt_all | QKV GEMM (deep-pipelined, RoPE fused) | transposed flash | out GEMM
//
// R1: both GEMMs moved from the m97 2-barrier structure (652 TF, MfmaUtil 27%,
// 1.9e7 bank conflicts, vmcnt drained every K-step) to a T2+T3+T4+T5 deep
// pipeline: BM=128 BN=256 BK=64, 512 thr / 8 waves (2Mx4N, per-wave 64x64),
// ring-2 LDS buffers (96 KB dynamic), 2 phases/K-tile, counted vmcnt(6)
// (loads stay in flight across barriers; drains 6->3->0 only in the tail),
// XOR-swizzled LDS reads (chunk ^= (row>>1)&3) with pre-swizzled glds source.
// Grid quantization exact at 1 block/CU: QKV 12x64=768=3x256, out 4x64=1x256.

#define D_MODEL 1024
#define NH      16
#define DKH     64
#define SEQ     2048
#define BATCH   4
#define M_ROWS  (BATCH * SEQ)   // 8192
#define SCALE_LOG2 0.180336875461f   // (1/sqrt(64)) * log2(e)
#define ROPE_L2    0.41524101186092029f  // log2(1e4)/32

typedef _Float16 f16;
typedef _Float16 f16x8 __attribute__((ext_vector_type(8)));
typedef _Float16 f16x4 __attribute__((ext_vector_type(4)));
typedef __fp16   fp16x2n __attribute__((ext_vector_type(2)));
typedef float    f32x4 __attribute__((ext_vector_type(4)));
typedef unsigned short u16;
typedef unsigned int   u32;

__device__ __forceinline__ void glds16(const void* g, void* l) {
  __builtin_amdgcn_global_load_lds((const __attribute__((address_space(1))) void*)g,
                                   (__attribute__((address_space(3))) void*)l, 16, 0, 0);
}
__device__ __forceinline__ u32 pk(float a, float b) {
  union { fp16x2n h; u32 u; } c; c.h = __builtin_amdgcn_cvt_pkrtz(a, b); return c.u;
}

// ---------------- f32 -> f16 convert: x (8192 blocks) + 4 weights (1024 each) ----
__global__ void cvt_all(const float* __restrict__ x,
                        const float* __restrict__ w0, const float* __restrict__ w1,
                        const float* __restrict__ w2, const float* __restrict__ w3,
                        f16* __restrict__ xo, f16* __restrict__ o0, f16* __restrict__ o1,
                        f16* __restrict__ o2, f16* __restrict__ o3) {
  int blk = blockIdx.x;
  const float* src; f16* dst; int off;
  if (blk < 8192) { src = x; dst = xo; off = blk; }
  else {
    int t = blk - 8192; int w = t >> 10; off = t & 1023;
    switch (w) { case 0: src = w0; dst = o0; break;  case 1: src = w1; dst = o1; break;
                 case 2: src = w2; dst = o2; break;  default: src = w3; dst = o3; break; }
  }
  int i = (off * 256 + threadIdx.x) * 4;
  float4 v = *(const float4*)(src + i);
  uint2 o; o.x = pk(v.x, v.y); o.y = pk(v.z, v.w);
  *(uint2*)(dst + i) = o;
}

// ---- deep-pipelined GEMM: C[M,N] = A[M,K] * W[N,K]^T ----
// LDS (dynamic 96 KB):
//   A[buf][h][128][32] f16 : off = buf*16384 + h*8192      (32 KB total)
//   B[buf][h][256][32] f16 : off = 32768 + buf*32768 + h*16384   (64 KB total)
// Swizzle: 16B chunk c at row r holds global chunk c ^ ((r>>1)&3); reads use
// the same XOR -> 8 distinct bank slots per 8 rows (2-way over 16 lanes = free).
// Stage groups: {A-half, B-half} = 3 glds/wave. Group for tile t's half h is
// issued at (t-1).ph(h+1), i.e. 2 phases before its consumption; the target
// region's last reader passed a barrier one phase before issue (WAR-safe).
// vmcnt(6) at each phase end = allow the 2 youngest groups, guaranteeing
// exactly the group needed after the barrier. Tail drains 6 -> 3 -> 0.
__device__ __forceinline__ void mfma16(f32x4 (&acc)[4][4], const f16x8 (&af)[4],
                                       const f16x8 (&bf)[4]) {
#pragma unroll
  for (int mi = 0; mi < 4; ++mi)
#pragma unroll
    for (int ni = 0; ni < 4; ++ni)
      acc[mi][ni] = __builtin_amdgcn_mfma_f32_16x16x32_f16(af[mi], bf[ni], acc[mi][ni], 0, 0, 0);
}

template<int MODE>
__global__ __launch_bounds__(512, 2) void gemm8p(const f16* __restrict__ A,
                                                 const f16* __restrict__ W,
                                                 void* __restrict__ C0,
                                                 void* __restrict__ C1,
                                                 void* __restrict__ C2,
                                                 const int* __restrict__ pos,
                                                 int K) {
  extern __shared__ char lds[];
  const int tid  = threadIdx.x;
  const int m0   = blockIdx.y * 128;
  const int n0   = blockIdx.x * 256;
  const int wave = tid >> 6, lane = tid & 63;
  const int quad = lane >> 4, l16 = lane & 15;
  const int wm = (wave >> 2) * 64;   // 0 / 64
  const int wn = (wave & 3) * 64;    // 0 / 64 / 128 / 192
  const int nt = K >> 6;             // K-tiles of 64 (nt >= 3 assumed; here 16)

  f32x4 acc[4][4];
#pragma unroll
  for (int i = 0; i < 4; ++i)
#pragma unroll
    for (int j = 0; j < 4; ++j) acc[i][j] = (f32x4){0.f, 0.f, 0.f, 0.f};

  // staging: LDS dest lane-linear (glds requirement), global source pre-swizzled
  auto stageA = [&](int t, int h) {                 // 8 KB, 1 glds/thread
    char* dst = lds + ((t & 1) * 16384 + h * 8192) + (size_t)(tid & 448) * 16;
    int r = tid >> 2, c = tid & 3;
    int g = c ^ ((r >> 1) & 3);
    glds16(A + (size_t)(m0 + r) * K + (t * 64 + h * 32) + g * 8, dst);
  };
  auto stageB = [&](int t, int h) {                 // 16 KB, 2 glds/thread
    char* base = lds + 32768 + ((t & 1) * 32768 + h * 16384);
#pragma unroll
    for (int j = 0; j < 2; ++j) {
      int ci = j * 512 + tid;
      int r = ci >> 2, c = ci & 3;
      int g = c ^ ((r >> 1) & 3);
      glds16(W + (size_t)(n0 + r) * K + (t * 64 + h * 32) + g * 8,
             base + (size_t)(j * 512 + (tid & 448)) * 16);
    }
  };
  auto readA = [&](int t, int h, int mi) -> f16x8 {
    int r = wm + mi * 16 + l16;
    int c = quad ^ ((r >> 1) & 3);
    return *(const f16x8*)(lds + (t & 1) * 16384 + h * 8192 + r * 64 + c * 16);
  };
  auto readB = [&](int t, int h, int ni) -> f16x8 {
    int r = wn + ni * 16 + l16;
    int c = quad ^ ((r >> 1) & 3);
    return *(const f16x8*)(lds + 32768 + (t & 1) * 32768 + h * 16384 + r * 64 + c * 16);
  };

  // prologue: t0.h0-group, t0.h1-group, t1.h0-group (9 vm-ops/wave)
  stageA(0, 0); stageB(0, 0);
  stageA(0, 1); stageB(0, 1);
  stageA(1, 0); stageB(1, 0);
  asm volatile("s_waitcnt vmcnt(6)" ::: "memory");   // t0.h0 landed
  __builtin_amdgcn_sched_barrier(0);
  __builtin_amdgcn_s_barrier();

  for (int t = 0; t < nt; ++t) {
    // ---------- phase 1: K-half 0 ----------
    {
      f16x8 af[4], bf[4];
#pragma unroll
      for (int i = 0; i < 4; ++i) { af[i] = readA(t, 0, i); bf[i] = readB(t, 0, i); }
      if (t + 1 < nt) { stageA(t + 1, 1); stageB(t + 1, 1); }   // (t+1).h1-group
      __builtin_amdgcn_s_barrier();
      asm volatile("s_waitcnt lgkmcnt(0)" ::: "memory");
      __builtin_amdgcn_sched_barrier(0);
      __builtin_amdgcn_s_setprio(1);
      mfma16(acc, af, bf);
      __builtin_amdgcn_s_setprio(0);
      if (t < nt - 1) asm volatile("s_waitcnt vmcnt(6)" ::: "memory"); // t.h1 landed
      else            asm volatile("s_waitcnt vmcnt(0)" ::: "memory");
      __builtin_amdgcn_sched_barrier(0);
      __builtin_amdgcn_s_barrier();
    }
    // ---------- phase 2: K-half 1 ----------
    {
      f16x8 af[4], bf[4];
#pragma unroll
      for (int i = 0; i < 4; ++i) { af[i] = readA(t, 1, i); bf[i] = readB(t, 1, i); }
      if (t + 2 < nt) { stageA(t + 2, 0); stageB(t + 2, 0); }   // (t+2).h0-group
      __builtin_amdgcn_s_barrier();
      asm volatile("s_waitcnt lgkmcnt(0)" ::: "memory");
      __builtin_amdgcn_sched_barrier(0);
      __builtin_amdgcn_s_setprio(1);
      mfma16(acc, af, bf);
      __builtin_amdgcn_s_setprio(0);
      if (t < nt - 1) {
        if (t < nt - 2) asm volatile("s_waitcnt vmcnt(6)" ::: "memory"); // (t+1).h0 landed
        else            asm volatile("s_waitcnt vmcnt(3)" ::: "memory");
        __builtin_amdgcn_sched_barrier(0);
        __builtin_amdgcn_s_barrier();
      }
    }
  }

  // epilogue: C layout col=lane&15, row=quad*4+reg (per-frag), cloned from the
  // verified m97-structure kernel; only wm/wn geometry changed.
  if (MODE == 1) {
    f16* dst; int nb;
    if (n0 < 1024)      { dst = (f16*)C0; nb = n0; }
    else if (n0 < 2048) { dst = (f16*)C1; nb = n0 - 1024; }
    else                { dst = (f16*)C2; nb = n0 - 2048; }
    if (n0 < 2048) {                         // Q or K: fused RoPE
      float invf[4], sgn[4];
#pragma unroll
      for (int ni = 0; ni < 4; ++ni) {
        int dk = (wn + ni * 16 + l16) & 63;
        invf[ni] = __builtin_amdgcn_exp2f(-ROPE_L2 * (float)(dk >> 1));
        sgn[ni]  = (dk & 1) ? 1.f : -1.f;
      }
#pragma unroll
      for (int mi = 0; mi < 4; ++mi)
#pragma unroll
        for (int r = 0; r < 4; ++r) {
          int row = m0 + wm + mi * 16 + quad * 4 + r;
          float ps = (float)pos[row & (SEQ - 1)];
#pragma unroll
          for (int ni = 0; ni < 4; ++ni) {
            float ang = ps * invf[ni];
            float c = __cosf(ang), sn = __sinf(ang);
            float v = acc[mi][ni][r];
            float p = __shfl_xor(v, 1);
            float ov = fmaf(p * sgn[ni], sn, v * c);
            int col = nb + wn + ni * 16 + l16;
            dst[(size_t)row * 1024 + col] = (f16)ov;
          }
        }
    } else {                                 // V: plain
#pragma unroll
      for (int mi = 0; mi < 4; ++mi)
#pragma unroll
        for (int ni = 0; ni < 4; ++ni)
#pragma unroll
          for (int r = 0; r < 4; ++r) {
            int row = m0 + wm + mi * 16 + quad * 4 + r;
            int col = nb + wn + ni * 16 + l16;
            dst[(size_t)row * 1024 + col] = (f16)acc[mi][ni][r];
          }
    }
  } else {
    float* dst = (float*)C0;
#pragma unroll
    for (int mi = 0; mi < 4; ++mi)
#pragma unroll
      for (int ni = 0; ni < 4; ++ni)
#pragma unroll
        for (int r = 0; r < 4; ++r) {
          int row = m0 + wm + mi * 16 + quad * 4 + r;
          int col = n0 + wn + ni * 16 + l16;
          dst[(size_t)row * 1024 + col] = acc[mi][ni][r];
        }
  }
}

// ---------------- transposed causal flash attention (unchanged) ----------------
__global__ __launch_bounds__(256, 3) void flash_attn(const f16* __restrict__ Q,
                                                     const f16* __restrict__ Kg,
                                                     const f16* __restrict__ Vg,
                                                     f16* __restrict__ O) {
  __shared__ char smem[38400];
  f16*  KsL         = (f16*)smem;                   // [128][64] key x dk (swizzled), 16 KB
  u32   (*Vt)[67]   = (u32(*)[67])(smem + 16384);   // [64 dk][67 key-pair], 17152 B
  float (*Red0)[66] = (float(*)[66])smem;           // [64 dk][66 q] waves 0,1 (aliases Ks)
  float (*Red1)[66] = (float(*)[66])(smem + 16896); // waves 2,3 (aliases Vt)
  float (*Lb)[17]   = (float(*)[17])(smem + 33792); // [64 q][17], cols 0..15 = wave*4+quad

  const int tid  = threadIdx.x;
  const int bh   = blockIdx.x;
  const int b    = bh >> 4, h = bh & 15;
  const int qblk = 31 - (int)blockIdx.y;          // longest first
  const int q0   = qblk * 64;
  const int wave = tid >> 6, lane = tid & 63;
  const int quad = lane >> 4, l16 = lane & 15;
  const int nkt  = (qblk + 2) >> 1;               // 128-key tiles covering q0+64 keys

  // Q B-frags (pre-scaled by SCALE_LOG2): B[k=dk][n=q] = Q[q=l16][dk=quad*8+j]
  f16x8 qf[4][2];
#pragma unroll
  for (int nt = 0; nt < 4; ++nt)
#pragma unroll
    for (int ks = 0; ks < 2; ++ks) {
      f16x8 qv = *(const f16x8*)(Q + ((size_t)(b * SEQ + q0 + nt * 16 + l16)) * D_MODEL
                                   + h * DKH + ks * 32 + quad * 8);
      qf[nt][ks] = qv * (f16)SCALE_LOG2;
    }

  f32x4 o[4][4];        // O^T partial: [dk-mtile][q-ntile], C layout dk=quad*4+r, q=l16
#pragma unroll
  for (int md = 0; md < 4; ++md)
#pragma unroll
    for (int nt = 0; nt < 4; ++nt) o[md][nt] = (f32x4){0.f, 0.f, 0.f, 0.f};
  float lacc[4] = {0.f, 0.f, 0.f, 0.f};

  const int kp = tid >> 3, dc = (tid & 7) * 8;    // V-transpose staging role

  for (int t = 0; t < nkt; ++t) {
    const int kt = t * 128;
    // V global loads early (keys 2kp,2kp+1 and 64+2kp,65+2kp; dk dc..dc+7)
    const f16* vb = Vg + ((size_t)(b * SEQ + kt + 2 * kp)) * D_MODEL + h * DKH + dc;
    uint4 v0 = *(const uint4*)vb;
    uint4 v1 = *(const uint4*)(vb + D_MODEL);
    uint4 v2 = *(const uint4*)(vb + 64 * D_MODEL);
    uint4 v3 = *(const uint4*)(vb + 65 * D_MODEL);

    if (t) __syncthreads();          // all waves done with prior Ks/Vt
    // K staging via glds16: LDS dest lane-linear, global chunk xor-swizzled
#pragma unroll
    for (int i = 0; i < 4; ++i) {
      int ci = i * 256 + tid;
      int row = ci >> 3, gc = (ci & 7) ^ (row & 7);
      glds16(Kg + ((size_t)(b * SEQ + kt + row)) * D_MODEL + h * DKH + gc * 8,
             smem + (size_t)(i * 256 + (tid & 192)) * 16);
    }
    {  // V transpose: key-pairs packed u32, [dk][kp], stride 67
      union { uint4 u; u16 s[8]; } a0, a1, a2, a3;
      a0.u = v0; a1.u = v1; a2.u = v2; a3.u = v3;
#pragma unroll
      for (int j = 0; j < 8; ++j) {
        Vt[dc + j][kp]      = (u32)a0.s[j] | ((u32)a1.s[j] << 16);
        Vt[dc + j][32 + kp] = (u32)a2.s[j] | ((u32)a3.s[j] << 16);
      }
    }
    __syncthreads();                 // also drains glds vmcnt

    // S^T = K_slice * Q^T (pre-scaled), exp2 -> P^T B-frags (registers only)
    f16x4 pb[2][4];
#pragma unroll
    for (int mt = 0; mt < 2; ++mt) {
      const int krow = wave * 32 + mt * 16 + l16;
      const int s0 = quad ^ (krow & 7);
      f16x8 ka0 = *(const f16x8*)(KsL + krow * 64 + s0 * 8);
      f16x8 ka1 = *(const f16x8*)(KsL + krow * 64 + (s0 ^ 4) * 8);
      const int keyb = kt + wave * 32 + mt * 16 + quad * 4;
#pragma unroll
      for (int nt = 0; nt < 4; ++nt) {
        f32x4 c = (f32x4){0.f, 0.f, 0.f, 0.f};
        c = __builtin_amdgcn_mfma_f32_16x16x32_f16(ka0, qf[nt][0], c, 0, 0, 0);
        c = __builtin_amdgcn_mfma_f32_16x16x32_f16(ka1, qf[nt][1], c, 0, 0, 0);
        const int q = q0 + nt * 16 + l16;
        float p0 = __builtin_amdgcn_exp2f(c[0]);
        float p1 = __builtin_amdgcn_exp2f(c[1]);
        float p2 = __builtin_amdgcn_exp2f(c[2]);
        float p3 = __builtin_amdgcn_exp2f(c[3]);
        if (t == nkt - 1) {          // causal mask (only last tile can clip)
          p0 = (keyb + 0 <= q) ? p0 : 0.f;
          p1 = (keyb + 1 <= q) ? p1 : 0.f;
          p2 = (keyb + 2 <= q) ? p2 : 0.f;
          p3 = (keyb + 3 <= q) ? p3 : 0.f;
        }
        lacc[nt] += (p0 + p1) + (p2 + p3);
        union { u32 w[2]; f16x4 v; } pp;
        pp.w[0] = pk(p0, p1); pp.w[1] = pk(p2, p3);
        pb[mt][nt] = pp.v;
      }
    }

    // O^T += V^T_slice * P^T  (16x16x16_f16, k = 16 keys per step)
#pragma unroll
    for (int md = 0; md < 4; ++md)
#pragma unroll
      for (int ks2 = 0; ks2 < 2; ++ks2) {
        const u32* vp = &Vt[md * 16 + l16][wave * 16 + ks2 * 8 + quad * 2];
        union { u32 x[2]; f16x4 v; } va;
        va.x[0] = vp[0]; va.x[1] = vp[1];
#pragma unroll
        for (int nt = 0; nt < 4; ++nt)
          o[md][nt] = __builtin_amdgcn_mfma_f32_16x16x16f16(va.v, pb[ks2][nt], o[md][nt], 0, 0, 0);
      }
  }

  __syncthreads();
  // cross-wave reduction: wave-pairs {0,1}->Red0, {2,3}->Red1; L fully parallel
  {
    float (*Rw)[66] = (wave >= 2) ? Red1 : Red0;
    if ((wave & 1) == 0) {           // waves 0,2 initialize
#pragma unroll
      for (int md = 0; md < 4; ++md)
#pragma unroll
        for (int nt = 0; nt < 4; ++nt)
#pragma unroll
          for (int r = 0; r < 4; ++r)
            Rw[md * 16 + quad * 4 + r][nt * 16 + l16] = o[md][nt][r];
    }
#pragma unroll
    for (int nt = 0; nt < 4; ++nt)
      Lb[nt * 16 + l16][wave * 4 + quad] = lacc[nt];
    __syncthreads();
    if (wave & 1) {                  // waves 1,3 accumulate
#pragma unroll
      for (int md = 0; md < 4; ++md)
#pragma unroll
        for (int nt = 0; nt < 4; ++nt)
#pragma unroll
          for (int r = 0; r < 4; ++r)
            Rw[md * 16 + quad * 4 + r][nt * 16 + l16] += o[md][nt][r];
    }
    __syncthreads();
  }

  // normalize + store: thread -> (q, 16-dk chunk), 32B contiguous
  {
    const int q = tid & 63, dc4 = (tid >> 6) * 16;
    float lsum = 0.f;
#pragma unroll
    for (int j = 0; j < 16; ++j) lsum += Lb[q][j];
    float linv = __builtin_amdgcn_rcpf(lsum);
    union { uint4 u[2]; u32 w[8]; } ov;
#pragma unroll
    for (int i = 0; i < 8; ++i) {
      float f0 = Red0[dc4 + 2 * i][q]     + Red1[dc4 + 2 * i][q];
      float f1 = Red0[dc4 + 2 * i + 1][q] + Red1[dc4 + 2 * i + 1][q];
      ov.w[i] = pk(f0 * linv, f1 * linv);
    }
    f16* op = O + ((size_t)(b * SEQ + q0 + q)) * D_MODEL + h * DKH + dc4;
    *(uint4*)op = ov.u[0];
    *(uint4*)(op + 8) = ov.u[1];
  }
}

// ---------------- launch ----------------
extern "C" void kernel_launch(void* const* d_in, const int* in_sizes, int n_in,
                              void* d_out, int out_size, void* d_ws, size_t ws_size,
                              hipStream_t stream) {
  const float* x      = (const float*)d_in[0];
  const int*   tokpos = (const int*)d_in[1];
  const float* wq     = (const float*)d_in[2];
  const float* wk     = (const float*)d_in[3];
  const float* wv     = (const float*)d_in[4];
  const float* wo     = (const float*)d_in[5];
  float* out = (float*)d_out;

  char* ws = (char*)d_ws;
  f16* Xb  = (f16*)(ws + 0);           // 16 MB (also Ob)
  f16* Wqb = (f16*)(ws + 16777216);    // Wq,Wk,Wv contiguous -> one [3072][1024]
  f16* Wkb = (f16*)(ws + 18874368);
  f16* Wvb = (f16*)(ws + 20971520);
  f16* Wob = (f16*)(ws + 23068672);
  f16* Qb  = (f16*)(ws + 25165824);
  f16* Kb  = (f16*)(ws + 41943040);
  f16* Vb  = (f16*)(ws + 58720256);
  f16* Ob  = Xb;

  static bool attr_done = false;
  if (!attr_done) {
    auto* f1 = gemm8p<1>;
    auto* f0 = gemm8p<0>;
    (void)hipFuncSetAttribute(reinterpret_cast<const void*>(f1),
                              hipFuncAttributeMaxDynamicSharedMemorySize, 98304);
    (void)hipFuncSetAttribute(reinterpret_cast<const void*>(f0),
                              hipFuncAttributeMaxDynamicSharedMemorySize, 98304);
    attr_done = true;
  }

  cvt_all<<<12288, 256, 0, stream>>>(x, wq, wk, wv, wo, Xb, Wqb, Wkb, Wvb, Wob);

  // fused QKV projection + RoPE: C[8192,3072] = X * Wqkv^T, split to Qb/Kb/Vb
  gemm8p<1><<<dim3(12, 64), 512, 98304, stream>>>(Xb, Wqb, Qb, Kb, Vb, tokpos, D_MODEL);

  flash_attn<<<dim3(BATCH * NH, 32), 256, 0, stream>>>(Qb, Kb, Vb, Ob);

  gemm8p<0><<<dim3(4, 64), 512, 98304, stream>>>(Ob, Wob, out, nullptr, nullptr, nullptr, D_MODEL);
}

// Round 2
// 252.526 us; speedup vs baseline: 1.0511x; 1.0511x over previous
//
#include <hip/hip_runtime.h>

// multihead self-attention: B=4 S=2048 D=1024 H=16 DK=64, causal, RoPE(theta=1e4)
// f16 pipeline, 4 dispatches:
//   cvt_all | QKV GEMM (deep-pipelined, RoPE fused) | transposed flash | out GEMM
//
// R2: R1's pipeline kept MfmaUtil at 27% because readA/readB took runtime t ->
// per-phase address VALU (~100 ops) dominated at 2 waves/SIMD. This round:
//  - compile-time addressing: NT=16 constant; swizzle col is mi/wm-invariant ->
//    1 base VGPR (A) + 2 (B h0/h1), every ds_read_b128 = base + imm offset;
//    stage pointers advance by constant 128 B/tile.
//  - merged phase: 1 phase per K-tile (16 reads, 32 MFMA, 6 glds, 2 barriers).
//  - ring-3 LDS (144 KB): stage lead-2 tiles requires 3 buffers once phases
//    merge (ring-2 would overwrite the buffer being read). vmcnt(6) counted
//    waits unchanged (6 glds/group, 2 groups in flight).
// Grid quantization exact at 1 block/CU: QKV 12x64=768=3x256, out 4x64=1x256.

#define D_MODEL 1024
#define NH      16
#define DKH     64
#define SEQ     2048
#define BATCH   4
#define M_ROWS  (BATCH * SEQ)   // 8192
#define SCALE_LOG2 0.180336875461f   // (1/sqrt(64)) * log2(e)
#define ROPE_L2    0.41524101186092029f  // log2(1e4)/32

typedef _Float16 f16;
typedef _Float16 f16x8 __attribute__((ext_vector_type(8)));
typedef _Float16 f16x4 __attribute__((ext_vector_type(4)));
typedef __fp16   fp16x2n __attribute__((ext_vector_type(2)));
typedef float    f32x4 __attribute__((ext_vector_type(4)));
typedef unsigned short u16;
typedef unsigned int   u32;

__device__ __forceinline__ void glds16(const void* g, void* l) {
  __builtin_amdgcn_global_load_lds((const __attribute__((address_space(1))) void*)g,
                                   (__attribute__((address_space(3))) void*)l, 16, 0, 0);
}
__device__ __forceinline__ u32 pk(float a, float b) {
  union { fp16x2n h; u32 u; } c; c.h = __builtin_amdgcn_cvt_pkrtz(a, b); return c.u;
}

// ---------------- f32 -> f16 convert: x (8192 blocks) + 4 weights (1024 each) ----
__global__ void cvt_all(const float* __restrict__ x,
                        const float* __restrict__ w0, const float* __restrict__ w1,
                        const float* __restrict__ w2, const float* __restrict__ w3,
                        f16* __restrict__ xo, f16* __restrict__ o0, f16* __restrict__ o1,
                        f16* __restrict__ o2, f16* __restrict__ o3) {
  int blk = blockIdx.x;
  const float* src; f16* dst; int off;
  if (blk < 8192) { src = x; dst = xo; off = blk; }
  else {
    int t = blk - 8192; int w = t >> 10; off = t & 1023;
    switch (w) { case 0: src = w0; dst = o0; break;  case 1: src = w1; dst = o1; break;
                 case 2: src = w2; dst = o2; break;  default: src = w3; dst = o3; break; }
  }
  int i = (off * 256 + threadIdx.x) * 4;
  float4 v = *(const float4*)(src + i);
  uint2 o; o.x = pk(v.x, v.y); o.y = pk(v.z, v.w);
  *(uint2*)(dst + i) = o;
}

// ---- deep-pipelined GEMM: C[M,N] = A[M,1024] * W[N,1024]^T, BM=128 BN=256 ----
// LDS ring-3 (144 KB dynamic):
//   A[buf][h][128][32] f16 : off = buf*16384 + h*8192                (48 KB)
//   B[h][buf][256][32] f16 : off = 49152 + h*49152 + buf*16384       (96 KB)
// Swizzle: 16B chunk c at row r holds global chunk c ^ ((r>>1)&3); reads use
// the same XOR. Read col offset (quad ^ ((l16>>1)&3))*16 is mi/wm/buf-invariant
// -> per-thread constant folded into the base registers.
// Per tile t (one phase): 16 ds_read_b128 + stage(t+2) [6 glds] + barrier +
// lgkmcnt(0) + 32 MFMA (setprio) + vmcnt(6) + barrier. Ring-3 WAR: stage(t+2)
// targets region (t+2)%3 whose last readers (tile t-1) drained lgkm before the
// end-of-(t-1) barrier, which precedes this stage. vmcnt(6) = 1 group of 6 in
// flight -> group t+1 landed at each phase end. Tail: vmcnt(0) at t=14.
template<int MODE>
__global__ __launch_bounds__(512, 2) void gemm8p(const f16* __restrict__ A,
                                                 const f16* __restrict__ W,
                                                 void* __restrict__ C0,
                                                 void* __restrict__ C1,
                                                 void* __restrict__ C2,
                                                 const int* __restrict__ pos) {
  extern __shared__ char lds[];
  const int tid  = threadIdx.x;
  const int m0   = blockIdx.y * 128;
  const int n0   = blockIdx.x * 256;
  const int wave = tid >> 6, lane = tid & 63;
  const int quad = lane >> 4, l16 = lane & 15;
  const int wm = (wave >> 2) * 64;   // 0 / 64
  const int wn = (wave & 3) * 64;    // 0 / 64 / 128 / 192

  f32x4 acc[4][4];
#pragma unroll
  for (int i = 0; i < 4; ++i)
#pragma unroll
    for (int j = 0; j < 4; ++j) acc[i][j] = (f32x4){0.f, 0.f, 0.f, 0.f};

  // per-thread constant bases (swizzled col is invariant in mi/wm/buf)
  const int cswr = (quad ^ ((l16 >> 1) & 3)) * 16;
  const char* aB  = lds + (wm + l16) * 64 + cswr;            // + buf*16384 + h*8192 + mi*1024
  const char* bB0 = lds + 49152 + (wn + l16) * 64 + cswr;    // + buf*16384 + ni*1024
  const char* bB1 = bB0 + 49152;

  // staging: LDS dest lane-linear (glds requirement), global source pre-swizzled
  const int sr = tid >> 2;
  const int sg = (tid & 3) ^ ((sr >> 1) & 3);
  const char* pA = (const char*)(A + (size_t)(m0 + sr) * 1024 + sg * 8);
  const char* pB = (const char*)(W + (size_t)(n0 + sr) * 1024 + sg * 8);
  char* const sA = lds + (size_t)(tid & 448) * 16;           // + SBUF*16384 (+8192 h1)
  char* const sB = lds + 49152 + (size_t)(tid & 448) * 16;   // + SBUF*16384 (+8192 j1, +49152 h1)

#define STAGE(SBUF) do {                                                      \
    glds16(pA,                sA + (SBUF) * 16384);                           \
    glds16(pA + 64,           sA + (SBUF) * 16384 + 8192);                    \
    glds16(pB,                sB + (SBUF) * 16384);                           \
    glds16(pB + 262144,       sB + (SBUF) * 16384 + 8192);                    \
    glds16(pB + 64,           sB + (SBUF) * 16384 + 49152);                   \
    glds16(pB + 262144 + 64,  sB + (SBUF) * 16384 + 49152 + 8192);            \
    pA += 128; pB += 128;                                                     \
  } while (0)

#define GPHASE(BUF, SBUF, DOSTAGE, VMN, LASTP) do {                           \
    f16x8 af[4][2], bf[4][2];                                                 \
    _Pragma("unroll")                                                         \
    for (int mi = 0; mi < 4; ++mi) {                                          \
      af[mi][0] = *(const f16x8*)(aB + ((BUF) * 16384 + mi * 1024));          \
      af[mi][1] = *(const f16x8*)(aB + ((BUF) * 16384 + 8192 + mi * 1024));   \
    }                                                                         \
    _Pragma("unroll")                                                         \
    for (int ni = 0; ni < 4; ++ni) {                                          \
      bf[ni][0] = *(const f16x8*)(bB0 + ((BUF) * 16384 + ni * 1024));         \
      bf[ni][1] = *(const f16x8*)(bB1 + ((BUF) * 16384 + ni * 1024));         \
    }                                                                         \
    if (DOSTAGE) STAGE(SBUF);                                                 \
    __builtin_amdgcn_s_barrier();                                             \
    asm volatile("s_waitcnt lgkmcnt(0)" ::: "memory");                        \
    __builtin_amdgcn_sched_barrier(0);                                        \
    __builtin_amdgcn_s_setprio(1);                                            \
    _Pragma("unroll")                                                         \
    for (int h = 0; h < 2; ++h)                                               \
      _Pragma("unroll")                                                       \
      for (int mi = 0; mi < 4; ++mi)                                          \
        _Pragma("unroll")                                                     \
        for (int ni = 0; ni < 4; ++ni)                                        \
          acc[mi][ni] = __builtin_amdgcn_mfma_f32_16x16x32_f16(af[mi][h], bf[ni][h], \
                                                               acc[mi][ni], 0, 0, 0); \
    __builtin_amdgcn_s_setprio(0);                                            \
    if (!(LASTP)) {                                                           \
      asm volatile("s_waitcnt vmcnt(" #VMN ")" ::: "memory");                 \
      __builtin_amdgcn_sched_barrier(0);                                      \
      __builtin_amdgcn_s_barrier();                                           \
    }                                                                         \
  } while (0)

  // prologue: stage tiles 0,1; wait group0; barrier
  STAGE(0);
  STAGE(1);
  asm volatile("s_waitcnt vmcnt(6)" ::: "memory");
  __builtin_amdgcn_sched_barrier(0);
  __builtin_amdgcn_s_barrier();

  // tiles 0..11 (buf pattern 0,1,2), then peeled tail 12,13,14,15
#pragma unroll 1
  for (int it = 0; it < 4; ++it) {
    GPHASE(0, 2, 1, 6, 0);
    GPHASE(1, 0, 1, 6, 0);
    GPHASE(2, 1, 1, 6, 0);
  }
  GPHASE(0, 2, 1, 6, 0);   // t=12, stages 14
  GPHASE(1, 0, 1, 6, 0);   // t=13, stages 15
  GPHASE(2, 0, 0, 0, 0);   // t=14, no stage, drain (group 15 lands)
  GPHASE(0, 0, 0, 0, 1);   // t=15, last: no trailing wait/barrier

#undef GPHASE
#undef STAGE

  // epilogue: C layout col=lane&15, row=quad*4+reg (per-frag); verified layout
  if (MODE == 1) {
    f16* dst; int nb;
    if (n0 < 1024)      { dst = (f16*)C0; nb = n0; }
    else if (n0 < 2048) { dst = (f16*)C1; nb = n0 - 1024; }
    else                { dst = (f16*)C2; nb = n0 - 2048; }
    if (n0 < 2048) {                         // Q or K: fused RoPE
      float invf[4], sgn[4];
#pragma unroll
      for (int ni = 0; ni < 4; ++ni) {
        int dk = (wn + ni * 16 + l16) & 63;
        invf[ni] = __builtin_amdgcn_exp2f(-ROPE_L2 * (float)(dk >> 1));
        sgn[ni]  = (dk & 1) ? 1.f : -1.f;
      }
#pragma unroll
      for (int mi = 0; mi < 4; ++mi)
#pragma unroll
        for (int r = 0; r < 4; ++r) {
          int row = m0 + wm + mi * 16 + quad * 4 + r;
          float ps = (float)pos[row & (SEQ - 1)];
#pragma unroll
          for (int ni = 0; ni < 4; ++ni) {
            float ang = ps * invf[ni];
            float c = __cosf(ang), sn = __sinf(ang);
            float v = acc[mi][ni][r];
            float p = __shfl_xor(v, 1);
            float ov = fmaf(p * sgn[ni], sn, v * c);
            int col = nb + wn + ni * 16 + l16;
            dst[(size_t)row * 1024 + col] = (f16)ov;
          }
        }
    } else {                                 // V: plain
#pragma unroll
      for (int mi = 0; mi < 4; ++mi)
#pragma unroll
        for (int ni = 0; ni < 4; ++ni)
#pragma unroll
          for (int r = 0; r < 4; ++r) {
            int row = m0 + wm + mi * 16 + quad * 4 + r;
            int col = nb + wn + ni * 16 + l16;
            dst[(size_t)row * 1024 + col] = (f16)acc[mi][ni][r];
          }
    }
  } else {
    float* dst = (float*)C0;
#pragma unroll
    for (int mi = 0; mi < 4; ++mi)
#pragma unroll
      for (int ni = 0; ni < 4; ++ni)
#pragma unroll
        for (int r = 0; r < 4; ++r) {
          int row = m0 + wm + mi * 16 + quad * 4 + r;
          int col = n0 + wn + ni * 16 + l16;
          dst[(size_t)row * 1024 + col] = acc[mi][ni][r];
        }
  }
}

// ---------------- transposed causal flash attention (unchanged) ----------------
__global__ __launch_bounds__(256, 3) void flash_attn(const f16* __restrict__ Q,
                                                     const f16* __restrict__ Kg,
                                                     const f16* __restrict__ Vg,
                                                     f16* __restrict__ O) {
  __shared__ char smem[38400];
  f16*  KsL         = (f16*)smem;                   // [128][64] key x dk (swizzled), 16 KB
  u32   (*Vt)[67]   = (u32(*)[67])(smem + 16384);   // [64 dk][67 key-pair], 17152 B
  float (*Red0)[66] = (float(*)[66])smem;           // [64 dk][66 q] waves 0,1 (aliases Ks)
  float (*Red1)[66] = (float(*)[66])(smem + 16896); // waves 2,3 (aliases Vt)
  float (*Lb)[17]   = (float(*)[17])(smem + 33792); // [64 q][17], cols 0..15 = wave*4+quad

  const int tid  = threadIdx.x;
  const int bh   = blockIdx.x;
  const int b    = bh >> 4, h = bh & 15;
  const int qblk = 31 - (int)blockIdx.y;          // longest first
  const int q0   = qblk * 64;
  const int wave = tid >> 6, lane = tid & 63;
  const int quad = lane >> 4, l16 = lane & 15;
  const int nkt  = (qblk + 2) >> 1;               // 128-key tiles covering q0+64 keys

  // Q B-frags (pre-scaled by SCALE_LOG2): B[k=dk][n=q] = Q[q=l16][dk=quad*8+j]
  f16x8 qf[4][2];
#pragma unroll
  for (int nt = 0; nt < 4; ++nt)
#pragma unroll
    for (int ks = 0; ks < 2; ++ks) {
      f16x8 qv = *(const f16x8*)(Q + ((size_t)(b * SEQ + q0 + nt * 16 + l16)) * D_MODEL
                                   + h * DKH + ks * 32 + quad * 8);
      qf[nt][ks] = qv * (f16)SCALE_LOG2;
    }

  f32x4 o[4][4];        // O^T partial: [dk-mtile][q-ntile], C layout dk=quad*4+r, q=l16
#pragma unroll
  for (int md = 0; md < 4; ++md)
#pragma unroll
    for (int nt = 0; nt < 4; ++nt) o[md][nt] = (f32x4){0.f, 0.f, 0.f, 0.f};
  float lacc[4] = {0.f, 0.f, 0.f, 0.f};

  const int kp = tid >> 3, dc = (tid & 7) * 8;    // V-transpose staging role

  for (int t = 0; t < nkt; ++t) {
    const int kt = t * 128;
    // V global loads early (keys 2kp,2kp+1 and 64+2kp,65+2kp; dk dc..dc+7)
    const f16* vb = Vg + ((size_t)(b * SEQ + kt + 2 * kp)) * D_MODEL + h * DKH + dc;
    uint4 v0 = *(const uint4*)vb;
    uint4 v1 = *(const uint4*)(vb + D_MODEL);
    uint4 v2 = *(const uint4*)(vb + 64 * D_MODEL);
    uint4 v3 = *(const uint4*)(vb + 65 * D_MODEL);

    if (t) __syncthreads();          // all waves done with prior Ks/Vt
    // K staging via glds16: LDS dest lane-linear, global chunk xor-swizzled
#pragma unroll
    for (int i = 0; i < 4; ++i) {
      int ci = i * 256 + tid;
      int row = ci >> 3, gc = (ci & 7) ^ (row & 7);
      glds16(Kg + ((size_t)(b * SEQ + kt + row)) * D_MODEL + h * DKH + gc * 8,
             smem + (size_t)(i * 256 + (tid & 192)) * 16);
    }
    {  // V transpose: key-pairs packed u32, [dk][kp], stride 67
      union { uint4 u; u16 s[8]; } a0, a1, a2, a3;
      a0.u = v0; a1.u = v1; a2.u = v2; a3.u = v3;
#pragma unroll
      for (int j = 0; j < 8; ++j) {
        Vt[dc + j][kp]      = (u32)a0.s[j] | ((u32)a1.s[j] << 16);
        Vt[dc + j][32 + kp] = (u32)a2.s[j] | ((u32)a3.s[j] << 16);
      }
    }
    __syncthreads();                 // also drains glds vmcnt

    // S^T = K_slice * Q^T (pre-scaled), exp2 -> P^T B-frags (registers only)
    f16x4 pb[2][4];
#pragma unroll
    for (int mt = 0; mt < 2; ++mt) {
      const int krow = wave * 32 + mt * 16 + l16;
      const int s0 = quad ^ (krow & 7);
      f16x8 ka0 = *(const f16x8*)(KsL + krow * 64 + s0 * 8);
      f16x8 ka1 = *(const f16x8*)(KsL + krow * 64 + (s0 ^ 4) * 8);
      const int keyb = kt + wave * 32 + mt * 16 + quad * 4;
#pragma unroll
      for (int nt = 0; nt < 4; ++nt) {
        f32x4 c = (f32x4){0.f, 0.f, 0.f, 0.f};
        c = __builtin_amdgcn_mfma_f32_16x16x32_f16(ka0, qf[nt][0], c, 0, 0, 0);
        c = __builtin_amdgcn_mfma_f32_16x16x32_f16(ka1, qf[nt][1], c, 0, 0, 0);
        const int q = q0 + nt * 16 + l16;
        float p0 = __builtin_amdgcn_exp2f(c[0]);
        float p1 = __builtin_amdgcn_exp2f(c[1]);
        float p2 = __builtin_amdgcn_exp2f(c[2]);
        float p3 = __builtin_amdgcn_exp2f(c[3]);
        if (t == nkt - 1) {          // causal mask (only last tile can clip)
          p0 = (keyb + 0 <= q) ? p0 : 0.f;
          p1 = (keyb + 1 <= q) ? p1 : 0.f;
          p2 = (keyb + 2 <= q) ? p2 : 0.f;
          p3 = (keyb + 3 <= q) ? p3 : 0.f;
        }
        lacc[nt] += (p0 + p1) + (p2 + p3);
        union { u32 w[2]; f16x4 v; } pp;
        pp.w[0] = pk(p0, p1); pp.w[1] = pk(p2, p3);
        pb[mt][nt] = pp.v;
      }
    }

    // O^T += V^T_slice * P^T  (16x16x16_f16, k = 16 keys per step)
#pragma unroll
    for (int md = 0; md < 4; ++md)
#pragma unroll
      for (int ks2 = 0; ks2 < 2; ++ks2) {
        const u32* vp = &Vt[md * 16 + l16][wave * 16 + ks2 * 8 + quad * 2];
        union { u32 x[2]; f16x4 v; } va;
        va.x[0] = vp[0]; va.x[1] = vp[1];
#pragma unroll
        for (int nt = 0; nt < 4; ++nt)
          o[md][nt] = __builtin_amdgcn_mfma_f32_16x16x16f16(va.v, pb[ks2][nt], o[md][nt], 0, 0, 0);
      }
  }

  __syncthreads();
  // cross-wave reduction: wave-pairs {0,1}->Red0, {2,3}->Red1; L fully parallel
  {
    float (*Rw)[66] = (wave >= 2) ? Red1 : Red0;
    if ((wave & 1) == 0) {           // waves 0,2 initialize
#pragma unroll
      for (int md = 0; md < 4; ++md)
#pragma unroll
        for (int nt = 0; nt < 4; ++nt)
#pragma unroll
          for (int r = 0; r < 4; ++r)
            Rw[md * 16 + quad * 4 + r][nt * 16 + l16] = o[md][nt][r];
    }
#pragma unroll
    for (int nt = 0; nt < 4; ++nt)
      Lb[nt * 16 + l16][wave * 4 + quad] = lacc[nt];
    __syncthreads();
    if (wave & 1) {                  // waves 1,3 accumulate
#pragma unroll
      for (int md = 0; md < 4; ++md)
#pragma unroll
        for (int nt = 0; nt < 4; ++nt)
#pragma unroll
          for (int r = 0; r < 4; ++r)
            Rw[md * 16 + quad * 4 + r][nt * 16 + l16] += o[md][nt][r];
    }
    __syncthreads();
  }

  // normalize + store: thread -> (q, 16-dk chunk), 32B contiguous
  {
    const int q = tid & 63, dc4 = (tid >> 6) * 16;
    float lsum = 0.f;
#pragma unroll
    for (int j = 0; j < 16; ++j) lsum += Lb[q][j];
    float linv = __builtin_amdgcn_rcpf(lsum);
    union { uint4 u[2]; u32 w[8]; } ov;
#pragma unroll
    for (int i = 0; i < 8; ++i) {
      float f0 = Red0[dc4 + 2 * i][q]     + Red1[dc4 + 2 * i][q];
      float f1 = Red0[dc4 + 2 * i + 1][q] + Red1[dc4 + 2 * i + 1][q];
      ov.w[i] = pk(f0 * linv, f1 * linv);
    }
    f16* op = O + ((size_t)(b * SEQ + q0 + q)) * D_MODEL + h * DKH + dc4;
    *(uint4*)op = ov.u[0];
    *(uint4*)(op + 8) = ov.u[1];
  }
}

// ---------------- launch ----------------
extern "C" void kernel_launch(void* const* d_in, const int* in_sizes, int n_in,
                              void* d_out, int out_size, void* d_ws, size_t ws_size,
                              hipStream_t stream) {
  const float* x      = (const float*)d_in[0];
  const int*   tokpos = (const int*)d_in[1];
  const float* wq     = (const float*)d_in[2];
  const float* wk     = (const float*)d_in[3];
  const float* wv     = (const float*)d_in[4];
  const float* wo     = (const float*)d_in[5];
  float* out = (float*)d_out;

  char* ws = (char*)d_ws;
  f16* Xb  = (f16*)(ws + 0);           // 16 MB (also Ob)
  f16* Wqb = (f16*)(ws + 16777216);    // Wq,Wk,Wv contiguous -> one [3072][1024]
  f16* Wkb = (f16*)(ws + 18874368);
  f16* Wvb = (f16*)(ws + 20971520);
  f16* Wob = (f16*)(ws + 23068672);
  f16* Qb  = (f16*)(ws + 25165824);
  f16* Kb  = (f16*)(ws + 41943040);
  f16* Vb  = (f16*)(ws + 58720256);
  f16* Ob  = Xb;

  static bool attr_done = false;
  if (!attr_done) {
    auto* f1 = gemm8p<1>;
    auto* f0 = gemm8p<0>;
    (void)hipFuncSetAttribute(reinterpret_cast<const void*>(f1),
                              hipFuncAttributeMaxDynamicSharedMemorySize, 147456);
    (void)hipFuncSetAttribute(reinterpret_cast<const void*>(f0),
                              hipFuncAttributeMaxDynamicSharedMemorySize, 147456);
    attr_done = true;
  }

  cvt_all<<<12288, 256, 0, stream>>>(x, wq, wk, wv, wo, Xb, Wqb, Wkb, Wvb, Wob);

  // fused QKV projection + RoPE: C[8192,3072] = X * Wqkv^T, split to Qb/Kb/Vb
  gemm8p<1><<<dim3(12, 64), 512, 147456, stream>>>(Xb, Wqb, Qb, Kb, Vb, tokpos);

  flash_attn<<<dim3(BATCH * NH, 32), 256, 0, stream>>>(Qb, Kb, Vb, Ob);

  gemm8p<0><<<dim3(4, 64), 512, 147456, stream>>>(Ob, Wob, out, nullptr, nullptr, nullptr);
}